// Round 5
// baseline (40.491 us; speedup 1.0000x reference)
//
#include <hip/hip_runtime.h>
#include <hip/hip_bf16.h>

// out = leaky( rowscale(adj) @ X @ W^T + b ),  B=16, N=1024, F_IN=F_OUT=128
// k1: Y = X @ W^T, written in MFMA-B-fragment layout (512-elem fragments).
// k2: 64-row blocks (grid 256 = 1/CU), EIGHT waves K-split (K=128 each),
//     LDS-free K-loop, two-stage cross-wave reduce in LDS at the end.
//
// yF fragment layout: fragment (b, ks, ot) at elem offset ((b*32+ks)*8+ot)*512,
//   lane l elems j=0..7 at +l*8+j hold Y[m = ks*32 + (l>>4)*8 + j][o = ot*16 + (l&15)]
//   -> k2 B-fragment load = base + lane*16B, fully coalesced.

typedef __attribute__((ext_vector_type(8))) __bf16 bf16x8;
typedef __attribute__((ext_vector_type(4))) float f32x4;

__device__ __forceinline__ unsigned f2bf_pk(float lo, float hi) {
    union { float f; unsigned u; } a, b;
    a.f = lo; b.f = hi;
    unsigned ra = (a.u + 0x7FFFu + ((a.u >> 16) & 1u)) >> 16;
    unsigned rb = (b.u + 0x7FFFu + ((b.u >> 16) & 1u)) & 0xFFFF0000u;
    return ra | rb;
}

__device__ __forceinline__ bf16x8 cvt8(const f32x4& a, const f32x4& b) {
    union { unsigned u[4]; bf16x8 v; } r;
    r.u[0] = f2bf_pk(a.x, a.y);
    r.u[1] = f2bf_pk(a.z, a.w);
    r.u[2] = f2bf_pk(b.x, b.y);
    r.u[3] = f2bf_pk(b.z, b.w);
    return r.v;
}

// ---------------- Kernel 1: Y = X @ W^T -> fragment layout ----------------
// grid 256 (16 batches x 16 row-blocks of 64), block 256 (4 waves, each 16 rows x 128 o)
__global__ __launch_bounds__(256, 2)
void k1_xw(const float* __restrict__ x, const float* __restrict__ W,
           unsigned short* __restrict__ yF)
{
    __shared__ unsigned short Ax[64 * 128];   // X tile [m][f] bf16, rows 256B, swizzled
    __shared__ unsigned short Bw[128 * 128];  // W      [o][f] bf16, rows 256B, swizzled

    const int t   = threadIdx.x;
    const int bid = blockIdx.x;
    const int xcd = bid & 7;
    const int j   = bid >> 3;
    const int b   = xcd * 2 + (j >> 4);
    const int m0  = (j & 15) << 6;
    const float* xb = x + (((long)b << 10) + m0) * 128;

#pragma unroll
    for (int i = 0; i < 8; ++i) {
        int e = i * 1024 + t * 4;
        int r = e >> 7, f = e & 127;
        f32x4 v = *(const f32x4*)(xb + (long)r * 128 + f);
        int c = f >> 3;
        int byte = r * 256 + (((c ^ (r & 7)) << 4) | ((f & 7) << 1));
        uint2 pk; pk.x = f2bf_pk(v.x, v.y); pk.y = f2bf_pk(v.z, v.w);
        *(uint2*)((char*)Ax + byte) = pk;
    }
#pragma unroll
    for (int i = 0; i < 16; ++i) {
        int e = i * 1024 + t * 4;
        int r = e >> 7, f = e & 127;
        f32x4 v = *(const f32x4*)(W + r * 128 + f);
        int c = f >> 3;
        int byte = r * 256 + (((c ^ (r & 7)) << 4) | ((f & 7) << 1));
        uint2 pk; pk.x = f2bf_pk(v.x, v.y); pk.y = f2bf_pk(v.z, v.w);
        *(uint2*)((char*)Bw + byte) = pk;
    }
    __syncthreads();

    const int lane = t & 63, w = t >> 6;
    const int lrow = lane & 15, lq = lane >> 4;

    bf16x8 af[4];
#pragma unroll
    for (int kk = 0; kk < 4; ++kk) {
        int r = w * 16 + lrow;
        int c = kk * 4 + lq;
        af[kk] = *(const bf16x8*)((const char*)Ax + r * 256 + ((c ^ (r & 7)) << 4));
    }

    f32x4 zero = {0.f, 0.f, 0.f, 0.f};
    f32x4 acc[8] = {zero, zero, zero, zero, zero, zero, zero, zero};
#pragma unroll
    for (int nf = 0; nf < 8; ++nf) {
#pragma unroll
        for (int kk = 0; kk < 4; ++kk) {
            int o = nf * 16 + lrow;
            int c = kk * 4 + lq;
            bf16x8 bfrag = *(const bf16x8*)((const char*)Bw + o * 256 + ((c ^ (o & 7)) << 4));
            acc[nf] = __builtin_amdgcn_mfma_f32_16x16x32_bf16(af[kk], bfrag, acc[nf], 0, 0, 0);
        }
    }

    // scatter into fragment layout:
    // lane holds Y[m = m0 + w*16 + lq*4 + i][o = nf*16 + lrow]
    {
        const int ks = (m0 >> 5) + (w >> 1);
        const int q  = (w & 1) * 2 + (lq >> 1);
        const int jb = (lq & 1) * 4;
#pragma unroll
        for (int nf = 0; nf < 8; ++nf) {
            uint2 pk;
            pk.x = f2bf_pk(acc[nf][0], acc[nf][1]);
            pk.y = f2bf_pk(acc[nf][2], acc[nf][3]);
            long off = (((long)((b * 32 + ks) * 8 + nf)) << 9) + (q * 16 + lrow) * 8 + jb;
            *(uint2*)(yF + off) = pk;
        }
    }
}

// ---------------- Kernel 2: out = leaky( invdeg * (adj @ Y) + bias ) ----------------
// grid 256 (1 block/CU), block 512 (8 waves, 2/SIMD). Wave w: K-range [w*128, +128),
// 4 row-groups x 8 o-tiles accumulators. LDS-free K-loop; two-stage LDS reduce:
// waves 0-3 write accbuf, waves 4-7 add in, then epilogue.
__global__ __launch_bounds__(512, 2)
void k2_agg(const float* __restrict__ adj, const unsigned short* __restrict__ yF,
            const float* __restrict__ bias, float* __restrict__ out)
{
    __shared__ float accbuf[4][128 * 68];   // 4 x 34816 B = 139264 B
    __shared__ float degw[8][64];

    const int bid = blockIdx.x;
    const int xcd = bid & 7;
    const int j   = bid >> 3;             // 0..31
    const int b   = xcd * 2 + (j >> 4);   // each XCD: 2 batches
    const int n0  = (j & 15) << 6;        // 64-row tile

    const int t = threadIdx.x;
    const int lane = t & 63, w = t >> 6;  // w = 0..7
    const int lrow = lane & 15, lq = lane >> 4;

    const float* adjr = adj + ((long)(b * 1024 + n0 + lrow)) * 1024 + (w << 7) + lq * 8;
    const unsigned short* fr = yF + (((long)(b * 32 + w * 4) * 8) << 9) + lane * 8;

    f32x4 zero = {0.f, 0.f, 0.f, 0.f};
    f32x4 acc[4][8];
#pragma unroll
    for (int rg = 0; rg < 4; ++rg)
#pragma unroll
        for (int ot = 0; ot < 8; ++ot) acc[rg][ot] = zero;
    float ds[4] = {0.f, 0.f, 0.f, 0.f};

#pragma unroll
    for (int kk = 0; kk < 4; ++kk) {
        f32x4 v0[4], v1[4];
#pragma unroll
        for (int rg = 0; rg < 4; ++rg) {
            v0[rg] = *(const f32x4*)(adjr + rg * 16384 + kk * 32);
            v1[rg] = *(const f32x4*)(adjr + rg * 16384 + kk * 32 + 4);
        }
        bf16x8 bb[8];
#pragma unroll
        for (int ot = 0; ot < 8; ++ot)
            bb[ot] = *(const bf16x8*)(fr + ((kk * 8 + ot) << 9));

        bf16x8 a[4];
#pragma unroll
        for (int rg = 0; rg < 4; ++rg) {
            ds[rg] += v0[rg].x + v0[rg].y + v0[rg].z + v0[rg].w
                    + v1[rg].x + v1[rg].y + v1[rg].z + v1[rg].w;
            a[rg] = cvt8(v0[rg], v1[rg]);
        }
#pragma unroll
        for (int rg = 0; rg < 4; ++rg)
#pragma unroll
            for (int ot = 0; ot < 8; ++ot)
                acc[rg][ot] = __builtin_amdgcn_mfma_f32_16x16x32_bf16(a[rg], bb[ot], acc[rg][ot], 0, 0, 0);
    }

    // per-row degree partials: reduce over the 4 lq groups sharing lrow
#pragma unroll
    for (int rg = 0; rg < 4; ++rg) {
        float d = ds[rg];
        d += __shfl_xor(d, 16, 64);
        d += __shfl_xor(d, 32, 64);
        if (lq == 0) degw[w][rg * 16 + lrow] = d;
    }

    // two-stage accumulator reduction, column-major [o][n] stride 68
    if (w < 4) {
#pragma unroll
        for (int rg = 0; rg < 4; ++rg)
#pragma unroll
            for (int ot = 0; ot < 8; ++ot)
                *(f32x4*)&accbuf[w][(ot * 16 + lrow) * 68 + rg * 16 + lq * 4] = acc[rg][ot];
    }
    __syncthreads();
    if (w >= 4) {
#pragma unroll
        for (int rg = 0; rg < 4; ++rg)
#pragma unroll
            for (int ot = 0; ot < 8; ++ot) {
                float* p = &accbuf[w - 4][(ot * 16 + lrow) * 68 + rg * 16 + lq * 4];
                f32x4 s = *(f32x4*)p;
                *(f32x4*)p = s + acc[rg][ot];
            }
    }
    __syncthreads();

    // epilogue: lane n = t&63 -> row n; wave w -> cols w*16 .. w*16+15
    {
        const int n = lane;
        const int o0 = w * 16;
        float deg = 0.f;
#pragma unroll
        for (int ww = 0; ww < 8; ++ww) deg += degw[ww][n];
        float inv = 1.0f / deg;
        float res[16];
#pragma unroll
        for (int c = 0; c < 16; ++c) {
            float s = accbuf[0][(o0 + c) * 68 + n] + accbuf[1][(o0 + c) * 68 + n]
                    + accbuf[2][(o0 + c) * 68 + n] + accbuf[3][(o0 + c) * 68 + n];
            float v = s * inv + bias[o0 + c];
            res[c] = (v >= 0.f) ? v : 0.01f * v;
        }
        float* op = out + (((long)(b * 1024 + n0 + n)) << 7) + o0;
#pragma unroll
        for (int g = 0; g < 4; ++g) {
            f32x4 r = {res[g * 4], res[g * 4 + 1], res[g * 4 + 2], res[g * 4 + 3]};
            *(f32x4*)(op + g * 4) = r;
        }
    }
}

extern "C" void kernel_launch(void* const* d_in, const int* in_sizes, int n_in,
                              void* d_out, int out_size, void* d_ws, size_t ws_size,
                              hipStream_t stream) {
    const float* node = (const float*)d_in[0];   // [16,1024,128]
    const float* adj  = (const float*)d_in[1];   // [16,1024,1024]
    const float* W    = (const float*)d_in[2];   // [128,128]
    const float* bias = (const float*)d_in[3];   // [128]
    float* out = (float*)d_out;                  // [16,1024,128]
    unsigned short* yF = (unsigned short*)d_ws;  // 16*32*8*512 bf16 = 4 MB scratch

    k1_xw<<<dim3(256), dim3(256), 0, stream>>>(node, W, yF);
    k2_agg<<<dim3(256), dim3(512), 0, stream>>>(adj, yF, bias, out);
}

// Round 6
// 29.424 us; speedup vs baseline: 1.3761x; 1.3761x over previous
//
#include <hip/hip_runtime.h>
#include <hip/hip_bf16.h>

// out = leaky( rowscale(adj) @ X @ W^T + b ),  B=16, N=1024, F_IN=F_OUT=128
// k1: Y = X @ W^T -> MFMA-B-fragment layout (512-elem fragments), grid 512.
// k2: 64-row blocks (grid 256 = 1 block/CU), block 512 = 8 waves (2/SIMD):
//     wave (h,q): rows [n0+h*32, +32), K range [q*256, +256), acc[2][8] = 64 VGPR.
//     LDS-free K-loop; 4-buffer cross-wave reduce (disjoint halves, no RMW).
//
// yF fragment layout: fragment (b, ks, ot) at elem offset ((b*32+ks)*8+ot)*512,
//   lane l elems j=0..7 at +l*8+j hold Y[m = ks*32 + (l>>4)*8 + j][o = ot*16 + (l&15)]
//   -> k2 B-fragment load = base + lane*16B, fully coalesced.

typedef __attribute__((ext_vector_type(8))) __bf16 bf16x8;
typedef __attribute__((ext_vector_type(4))) float f32x4;

__device__ __forceinline__ unsigned f2bf_pk(float lo, float hi) {
    union { float f; unsigned u; } a, b;
    a.f = lo; b.f = hi;
    unsigned ra = (a.u + 0x7FFFu + ((a.u >> 16) & 1u)) >> 16;
    unsigned rb = (b.u + 0x7FFFu + ((b.u >> 16) & 1u)) & 0xFFFF0000u;
    return ra | rb;
}

__device__ __forceinline__ bf16x8 cvt8(const f32x4& a, const f32x4& b) {
    union { unsigned u[4]; bf16x8 v; } r;
    r.u[0] = f2bf_pk(a.x, a.y);
    r.u[1] = f2bf_pk(a.z, a.w);
    r.u[2] = f2bf_pk(b.x, b.y);
    r.u[3] = f2bf_pk(b.z, b.w);
    return r.v;
}

// ---------------- Kernel 1: Y = X @ W^T -> fragment layout ----------------
// grid 512 (16 batches x 32 row-blocks of 32), block 256 (4 waves, 2x2 tiles 16x64)
__global__ __launch_bounds__(256, 2)
void k1_xw(const float* __restrict__ x, const float* __restrict__ W,
           unsigned short* __restrict__ yF)
{
    __shared__ unsigned short Ax[32 * 128];   // X tile [m][f] bf16, rows 256B, swizzled
    __shared__ unsigned short Bw[128 * 128];  // W      [o][f] bf16, rows 256B, swizzled

    const int t  = threadIdx.x;
    const int wg = blockIdx.x;
    const int b  = wg >> 5;
    const int m0 = (wg & 31) << 5;
    const float* xb = x + (((long)b << 10) + m0) * 128;

#pragma unroll
    for (int i = 0; i < 4; ++i) {
        int e = i * 1024 + t * 4;
        int r = e >> 7, f = e & 127;
        f32x4 v = *(const f32x4*)(xb + (long)r * 128 + f);
        int c = f >> 3;
        int byte = r * 256 + (((c ^ (r & 7)) << 4) | ((f & 7) << 1));
        uint2 pk; pk.x = f2bf_pk(v.x, v.y); pk.y = f2bf_pk(v.z, v.w);
        *(uint2*)((char*)Ax + byte) = pk;
    }
#pragma unroll
    for (int i = 0; i < 16; ++i) {
        int e = i * 1024 + t * 4;
        int r = e >> 7, f = e & 127;
        f32x4 v = *(const f32x4*)(W + r * 128 + f);
        int c = f >> 3;
        int byte = r * 256 + (((c ^ (r & 7)) << 4) | ((f & 7) << 1));
        uint2 pk; pk.x = f2bf_pk(v.x, v.y); pk.y = f2bf_pk(v.z, v.w);
        *(uint2*)((char*)Bw + byte) = pk;
    }
    __syncthreads();

    const int lane = t & 63, w = t >> 6;
    const int wm = w >> 1, wn = w & 1;
    const int lrow = lane & 15, lq = lane >> 4;

    bf16x8 af[4];
#pragma unroll
    for (int kk = 0; kk < 4; ++kk) {
        int r = wm * 16 + lrow;
        int c = kk * 4 + lq;
        af[kk] = *(const bf16x8*)((const char*)Ax + r * 256 + ((c ^ (r & 7)) << 4));
    }

    f32x4 zero = {0.f, 0.f, 0.f, 0.f};
    f32x4 acc[4] = {zero, zero, zero, zero};
#pragma unroll
    for (int nf = 0; nf < 4; ++nf) {
#pragma unroll
        for (int kk = 0; kk < 4; ++kk) {
            int o = wn * 64 + nf * 16 + lrow;
            int c = kk * 4 + lq;
            bf16x8 bfrag = *(const bf16x8*)((const char*)Bw + o * 256 + ((c ^ (o & 7)) << 4));
            acc[nf] = __builtin_amdgcn_mfma_f32_16x16x32_bf16(af[kk], bfrag, acc[nf], 0, 0, 0);
        }
    }

    // lane holds Y[m = m0 + wm*16 + lq*4 + i][o = wn*64 + nf*16 + lrow]
    {
        const int ks = wg & 31;
        const int q  = wm * 2 + (lq >> 1);
        const int jb = (lq & 1) * 4;
#pragma unroll
        for (int nf = 0; nf < 4; ++nf) {
            int ot = wn * 4 + nf;
            uint2 pk;
            pk.x = f2bf_pk(acc[nf][0], acc[nf][1]);
            pk.y = f2bf_pk(acc[nf][2], acc[nf][3]);
            long off = (((long)((b * 32 + ks) * 8 + ot)) << 9) + (q * 16 + lrow) * 8 + jb;
            *(uint2*)(yF + off) = pk;
        }
    }
}

// ---------------- Kernel 2: out = leaky( invdeg * (adj @ Y) + bias ) ----------------
// grid 256 (1 block/CU), block 512 (8 waves, 2/SIMD). Wave (h=w>>2, q=w&3):
// rows [n0+h*32, +32) x K [q*256, +256), acc[2][8]. One barrier; 4-buffer reduce.
__global__ __launch_bounds__(512, 2)
void k2_agg(const float* __restrict__ adj, const unsigned short* __restrict__ yF,
            const float* __restrict__ bias, float* __restrict__ out)
{
    __shared__ float accbuf[4][128 * 68];   // per-q buffers, col-major [o][n] stride 68
    __shared__ float degw[4][64];

    const int bid = blockIdx.x;
    const int xcd = bid & 7;
    const int j   = bid >> 3;             // 0..31
    const int b   = xcd * 2 + (j >> 4);   // each XCD: 2 batches
    const int n0  = (j & 15) << 6;        // 64-row tile

    const int t = threadIdx.x;
    const int lane = t & 63, w = t >> 6;  // w = 0..7
    const int h = w >> 2, q = w & 3;
    const int lrow = lane & 15, lq = lane >> 4;

    const float* adjr = adj + ((long)(b * 1024 + n0 + h * 32 + lrow)) * 1024 + (q << 8) + lq * 8;
    const unsigned short* fr = yF + (((long)((b * 32 + q * 8) * 8)) << 9) + lane * 8;

    f32x4 zero = {0.f, 0.f, 0.f, 0.f};
    f32x4 acc[2][8];
#pragma unroll
    for (int rg = 0; rg < 2; ++rg)
#pragma unroll
        for (int ot = 0; ot < 8; ++ot) acc[rg][ot] = zero;
    float ds[2] = {0.f, 0.f};

#pragma unroll
    for (int kk = 0; kk < 8; ++kk) {
        f32x4 v0[2], v1[2];
#pragma unroll
        for (int rg = 0; rg < 2; ++rg) {
            v0[rg] = *(const f32x4*)(adjr + rg * 16384 + kk * 32);
            v1[rg] = *(const f32x4*)(adjr + rg * 16384 + kk * 32 + 4);
        }
        bf16x8 bb[8];
#pragma unroll
        for (int ot = 0; ot < 8; ++ot)
            bb[ot] = *(const bf16x8*)(fr + ((kk * 8 + ot) << 9));

        bf16x8 a[2];
#pragma unroll
        for (int rg = 0; rg < 2; ++rg) {
            ds[rg] += v0[rg].x + v0[rg].y + v0[rg].z + v0[rg].w
                    + v1[rg].x + v1[rg].y + v1[rg].z + v1[rg].w;
            a[rg] = cvt8(v0[rg], v1[rg]);
        }
#pragma unroll
        for (int rg = 0; rg < 2; ++rg)
#pragma unroll
            for (int ot = 0; ot < 8; ++ot)
                acc[rg][ot] = __builtin_amdgcn_mfma_f32_16x16x32_bf16(a[rg], bb[ot], acc[rg][ot], 0, 0, 0);
    }

    // per-row degree partials (rows h*32 + rg*16 + lrow, K-quarter q)
#pragma unroll
    for (int rg = 0; rg < 2; ++rg) {
        float d = ds[rg];
        d += __shfl_xor(d, 16, 64);
        d += __shfl_xor(d, 32, 64);
        if (lq == 0) degw[q][h * 32 + rg * 16 + lrow] = d;
    }

    // dump accumulators: buffer q, rows h*32.., col-major [o][n] stride 68
#pragma unroll
    for (int rg = 0; rg < 2; ++rg)
#pragma unroll
        for (int ot = 0; ot < 8; ++ot)
            *(f32x4*)&accbuf[q][(ot * 16 + lrow) * 68 + h * 32 + rg * 16 + lq * 4] = acc[rg][ot];
    __syncthreads();

    // epilogue: lane n = t&63 -> row n; wave w -> cols w*16 .. w*16+15
    {
        const int n = lane;
        const int o0 = w * 16;
        float deg = degw[0][n] + degw[1][n] + degw[2][n] + degw[3][n];
        float inv = 1.0f / deg;
        float res[16];
#pragma unroll
        for (int c = 0; c < 16; ++c) {
            float s = accbuf[0][(o0 + c) * 68 + n] + accbuf[1][(o0 + c) * 68 + n]
                    + accbuf[2][(o0 + c) * 68 + n] + accbuf[3][(o0 + c) * 68 + n];
            float v = s * inv + bias[o0 + c];
            res[c] = (v >= 0.f) ? v : 0.01f * v;
        }
        float* op = out + (((long)(b * 1024 + n0 + n)) << 7) + o0;
#pragma unroll
        for (int g = 0; g < 4; ++g) {
            f32x4 r = {res[g * 4], res[g * 4 + 1], res[g * 4 + 2], res[g * 4 + 3]};
            *(f32x4*)(op + g * 4) = r;
        }
    }
}

extern "C" void kernel_launch(void* const* d_in, const int* in_sizes, int n_in,
                              void* d_out, int out_size, void* d_ws, size_t ws_size,
                              hipStream_t stream) {
    const float* node = (const float*)d_in[0];   // [16,1024,128]
    const float* adj  = (const float*)d_in[1];   // [16,1024,1024]
    const float* W    = (const float*)d_in[2];   // [128,128]
    const float* bias = (const float*)d_in[3];   // [128]
    float* out = (float*)d_out;                  // [16,1024,128]
    unsigned short* yF = (unsigned short*)d_ws;  // 16*32*8*512 bf16 = 4 MB scratch

    k1_xw<<<dim3(512), dim3(256), 0, stream>>>(node, W, yF);
    k2_agg<<<dim3(256), dim3(512), 0, stream>>>(adj, yF, bias, out);
}

// Round 7
// 28.829 us; speedup vs baseline: 1.4045x; 1.0206x over previous
//
#include <hip/hip_runtime.h>
#include <hip/hip_bf16.h>

// out = leaky( rowscale(adj) @ X @ W^T + b ),  B=16, N=1024, F_IN=F_OUT=128
// k1: Y = X @ W^T -> MFMA-B-fragment layout (512-elem fragments), grid 256.
// k2: 64-row blocks (grid 256 = 1 block/CU), block 512 = 8 waves (2/SIMD).
//     Both operands staged via global_load_lds, double-buffered, K-step 128.
//     adj staged fp32 COALESCED with source-side XOR chunk swizzle (c ^= row&7)
//     so A-fragment ds_read_b128 is bank-uniform. Y staged per-fragment (wave-linear).
//     Wave (h = w>>1, oc = w&1): rows [h*16,+16) x cols [oc*64,+64) -> acc[4], no
//     cross-wave reduction. Degrees from the same LDS reads, shfl-reduced.
//
// yF fragment layout: fragment (b, ks, ot) at elem offset ((b*32+ks)*8+ot)*512,
//   lane l elems j=0..7 at +l*8+j hold Y[m = ks*32 + (l>>4)*8 + j][o = ot*16 + (l&15)]

typedef __attribute__((ext_vector_type(8))) __bf16 bf16x8;
typedef __attribute__((ext_vector_type(4))) float f32x4;

#define GLD16(gp, lp) __builtin_amdgcn_global_load_lds( \
    (const __attribute__((address_space(1))) unsigned int*)(gp), \
    (__attribute__((address_space(3))) unsigned int*)(lp), 16, 0, 0)

__device__ __forceinline__ unsigned f2bf_pk(float lo, float hi) {
    union { float f; unsigned u; } a, b;
    a.f = lo; b.f = hi;
    unsigned ra = (a.u + 0x7FFFu + ((a.u >> 16) & 1u)) >> 16;
    unsigned rb = (b.u + 0x7FFFu + ((b.u >> 16) & 1u)) & 0xFFFF0000u;
    return ra | rb;
}

__device__ __forceinline__ bf16x8 cvt8(const f32x4& a, const f32x4& b) {
    union { unsigned u[4]; bf16x8 v; } r;
    r.u[0] = f2bf_pk(a.x, a.y);
    r.u[1] = f2bf_pk(a.z, a.w);
    r.u[2] = f2bf_pk(b.x, b.y);
    r.u[3] = f2bf_pk(b.z, b.w);
    return r.v;
}

// ---------------- Kernel 1: Y = X @ W^T -> fragment layout ----------------
// grid 256 (16 batches x 16 row-blocks of 64), block 256 (4 waves, each 16 rows x 128 o)
__global__ __launch_bounds__(256, 2)
void k1_xw(const float* __restrict__ x, const float* __restrict__ W,
           unsigned short* __restrict__ yF)
{
    __shared__ unsigned short Ax[64 * 128];   // X tile [m][f] bf16, rows 256B, swizzled
    __shared__ unsigned short Bw[128 * 128];  // W      [o][f] bf16, rows 256B, swizzled

    const int t   = threadIdx.x;
    const int bid = blockIdx.x;
    const int xcd = bid & 7;
    const int j   = bid >> 3;
    const int b   = xcd * 2 + (j >> 4);
    const int m0  = (j & 15) << 6;
    const float* xb = x + (((long)b << 10) + m0) * 128;

#pragma unroll
    for (int i = 0; i < 8; ++i) {
        int e = i * 1024 + t * 4;
        int r = e >> 7, f = e & 127;
        f32x4 v = *(const f32x4*)(xb + (long)r * 128 + f);
        int c = f >> 3;
        int byte = r * 256 + (((c ^ (r & 7)) << 4) | ((f & 7) << 1));
        uint2 pk; pk.x = f2bf_pk(v.x, v.y); pk.y = f2bf_pk(v.z, v.w);
        *(uint2*)((char*)Ax + byte) = pk;
    }
#pragma unroll
    for (int i = 0; i < 16; ++i) {
        int e = i * 1024 + t * 4;
        int r = e >> 7, f = e & 127;
        f32x4 v = *(const f32x4*)(W + r * 128 + f);
        int c = f >> 3;
        int byte = r * 256 + (((c ^ (r & 7)) << 4) | ((f & 7) << 1));
        uint2 pk; pk.x = f2bf_pk(v.x, v.y); pk.y = f2bf_pk(v.z, v.w);
        *(uint2*)((char*)Bw + byte) = pk;
    }
    __syncthreads();

    const int lane = t & 63, w = t >> 6;
    const int lrow = lane & 15, lq = lane >> 4;

    bf16x8 af[4];
#pragma unroll
    for (int kk = 0; kk < 4; ++kk) {
        int r = w * 16 + lrow;
        int c = kk * 4 + lq;
        af[kk] = *(const bf16x8*)((const char*)Ax + r * 256 + ((c ^ (r & 7)) << 4));
    }

    f32x4 zero = {0.f, 0.f, 0.f, 0.f};
    f32x4 acc[8] = {zero, zero, zero, zero, zero, zero, zero, zero};
#pragma unroll
    for (int nf = 0; nf < 8; ++nf) {
#pragma unroll
        for (int kk = 0; kk < 4; ++kk) {
            int o = nf * 16 + lrow;
            int c = kk * 4 + lq;
            bf16x8 bfrag = *(const bf16x8*)((const char*)Bw + o * 256 + ((c ^ (o & 7)) << 4));
            acc[nf] = __builtin_amdgcn_mfma_f32_16x16x32_bf16(af[kk], bfrag, acc[nf], 0, 0, 0);
        }
    }

    // lane holds Y[m = m0 + w*16 + lq*4 + i][o = nf*16 + lrow]
    {
        const int ks = (m0 >> 5) + (w >> 1);
        const int q  = (w & 1) * 2 + (lq >> 1);
        const int jb = (lq & 1) * 4;
#pragma unroll
        for (int nf = 0; nf < 8; ++nf) {
            uint2 pk;
            pk.x = f2bf_pk(acc[nf][0], acc[nf][1]);
            pk.y = f2bf_pk(acc[nf][2], acc[nf][3]);
            long off = (((long)((b * 32 + ks) * 8 + nf)) << 9) + (q * 16 + lrow) * 8 + jb;
            *(uint2*)(yF + off) = pk;
        }
    }
}

// ---------------- Kernel 2: out = leaky( invdeg * (adj @ Y) + bias ) ----------------
__global__ __launch_bounds__(512, 2)
void k2_agg(const float* __restrict__ adj, const unsigned short* __restrict__ yF,
            const float* __restrict__ bias, float* __restrict__ out)
{
    __shared__ float          bufA[2][64 * 128];    // 2 x 32KB fp32 adj tiles (swizzled chunks)
    __shared__ unsigned short bufY[2][32 * 512];    // 2 x 32KB bf16 Y fragments

    const int bid = blockIdx.x;
    const int xcd = bid & 7;
    const int j   = bid >> 3;             // 0..31
    const int b   = xcd * 2 + (j >> 4);   // each XCD: 2 batches
    const int n0  = (j & 15) << 6;        // 64-row tile

    const int t = threadIdx.x;
    const int lane = t & 63, w = t >> 6;  // w = 0..7
    const int h = w >> 1, oc = w & 1;     // rowgroup, colhalf
    const int lrow = lane & 15, lq = lane >> 4;

    const float* adjb = adj + ((long)b << 20);  // batch base (1024*1024)

    // staging lane-constants
    const int srow = (lane >> 5);          // adj: sub-row within instr (0/1)
    const int ssc  = lane & 31;            // adj: stored chunk index

    f32x4 zero = {0.f, 0.f, 0.f, 0.f};
    f32x4 acc[4] = {zero, zero, zero, zero};
    float dsum = 0.f;

    // ---- staging: wave w<4 stages adj rows [w*16, +16); w>=4 stages Y frags ks=w-4
#define STAGE(BUF, S)                                                                  \
    do {                                                                               \
        if (w < 4) {                                                                   \
            _Pragma("unroll")                                                          \
            for (int i = 0; i < 8; ++i) {                                              \
                int rl = w * 16 + 2 * i + srow;                                        \
                const float* g = adjb + ((long)(n0 + rl) << 10) + (S) * 128            \
                               + ((ssc ^ (rl & 7)) << 2);                              \
                GLD16(g, &bufA[BUF][(w * 16 + 2 * i) * 128]);                          \
            }                                                                          \
        } else {                                                                       \
            const int ks = w - 4;                                                      \
            _Pragma("unroll")                                                          \
            for (int i = 0; i < 8; ++i) {                                              \
                const unsigned short* g = yF                                           \
                    + (((long)((b * 32 + (S) * 4 + ks) * 8 + i)) << 9) + lane * 8;     \
                GLD16(g, &bufY[BUF][(ks * 8 + i) << 9]);                               \
            }                                                                          \
        }                                                                              \
    } while (0)

    STAGE(0, 0);
    __syncthreads();

    for (int s = 0; s < 8; ++s) {
        const int cur = s & 1;
        if (s < 7) STAGE(cur ^ 1, s + 1);

        const int row = h * 16 + lrow;
        const int rx  = row & 7;
#pragma unroll
        for (int kk = 0; kk < 4; ++kk) {
            const int c0 = kk * 8 + lq * 2;
            f32x4 a0 = *(const f32x4*)&bufA[cur][row * 128 + ((c0 ^ rx) << 2)];
            f32x4 a1 = *(const f32x4*)&bufA[cur][row * 128 + (((c0 + 1) ^ rx) << 2)];
            dsum += a0.x + a0.y + a0.z + a0.w + a1.x + a1.y + a1.z + a1.w;
            bf16x8 a = cvt8(a0, a1);
#pragma unroll
            for (int n = 0; n < 4; ++n) {
                const int ot = oc * 4 + n;
                bf16x8 bb = *(const bf16x8*)&bufY[cur][((kk * 8 + ot) << 9) + lane * 8];
                acc[n] = __builtin_amdgcn_mfma_f32_16x16x32_bf16(a, bb, acc[n], 0, 0, 0);
            }
        }
        __syncthreads();
    }

    // dsum: lane covered row h*16+lrow, k-slices for its lq -> reduce over lq groups
    dsum += __shfl_xor(dsum, 16, 64);
    dsum += __shfl_xor(dsum, 32, 64);
    // invdeg for this lane's output rows (lq*4 + i): held by lane (lq*4+i) (lrow match)
    float invd[4];
#pragma unroll
    for (int i = 0; i < 4; ++i)
        invd[i] = 1.0f / __shfl(dsum, lq * 4 + i, 64);

    // epilogue: direct stores; lane (lq,lrow): rows h*16+lq*4+i, col ot*16+lrow
#pragma unroll
    for (int n = 0; n < 4; ++n) {
        const int o = (oc * 4 + n) * 16 + lrow;
        const float bv = bias[o];
#pragma unroll
        for (int i = 0; i < 4; ++i) {
            const int r = n0 + h * 16 + lq * 4 + i;
            float v = acc[n][i] * invd[i] + bv;
            v = (v >= 0.f) ? v : 0.01f * v;
            out[(((long)(b * 1024 + r)) << 7) + o] = v;
        }
    }
#undef STAGE
}

extern "C" void kernel_launch(void* const* d_in, const int* in_sizes, int n_in,
                              void* d_out, int out_size, void* d_ws, size_t ws_size,
                              hipStream_t stream) {
    const float* node = (const float*)d_in[0];   // [16,1024,128]
    const float* adj  = (const float*)d_in[1];   // [16,1024,1024]
    const float* W    = (const float*)d_in[2];   // [128,128]
    const float* bias = (const float*)d_in[3];   // [128]
    float* out = (float*)d_out;                  // [16,1024,128]
    unsigned short* yF = (unsigned short*)d_ws;  // 16*32*8*512 bf16 = 4 MB scratch

    k1_xw<<<dim3(256), dim3(256), 0, stream>>>(node, W, yF);
    k2_agg<<<dim3(256), dim3(512), 0, stream>>>(adj, yF, bias, out);
}